// Round 5
// baseline (130.880 us; speedup 1.0000x reference)
//
#include <hip/hip_runtime.h>
#include <hip/hip_bf16.h>

#define CIN   128
#define HH    64
#define WW    64
#define COUT  256
#define HO    64
#define WO    64
#define NTAP  9
#define KTOT  (CIN*NTAP)   /* 1152 */
#define BK    32
#define NSTEP (KTOT/BK)    /* 36 */
#define HSTEP (NSTEP/2)    /* 18 per half-block */
#define NB    8

typedef __attribute__((ext_vector_type(8))) short bf16x8;
typedef __attribute__((ext_vector_type(4))) short bf16x4;
typedef __attribute__((ext_vector_type(4))) float f32x4;

struct __align__(16) TapEntry {
  int   i00, i01, i10, i11;    // BYTE offsets into xt's per-image slice
  float w00, w01, w10, w11;
};

static __device__ __forceinline__ ushort f2bf(float v) {
  unsigned u = __float_as_uint(v);
  unsigned rnd = 0x7fffu + ((u >> 16) & 1u);
  return (ushort)((u + rnd) >> 16);
}
static __device__ __forceinline__ float bf2f(short s) {
  return __uint_as_float(((unsigned)(unsigned short)s) << 16);
}

// ---- prep: fused x NCHW f32 -> xt NHWC bf16  +  weight repack ----
__global__ __launch_bounds__(256) void prep(const float* __restrict__ x,
                                            const float* __restrict__ w,
                                            ushort* __restrict__ xt,
                                            ushort* __restrict__ wb) {
  const int blk = blockIdx.x;
  const int tid = threadIdx.x;
  if (blk < NB * HH) {
    const int b = blk >> 6, y = blk & 63;
    const int px = tid & 63, c8 = tid >> 6;
    const float* src = x + (size_t)b * CIN * HH * WW + y * WW + px;
    ushort* dst = xt + (((size_t)(b * HH + y) * WW) + px) * CIN;
    #pragma unroll
    for (int cc = 0; cc < 4; ++cc) {
      const int c0 = cc * 32 + c8 * 8;
      bf16x8 v;
      #pragma unroll
      for (int j = 0; j < 8; ++j)
        v[j] = (short)f2bf(src[(size_t)(c0 + j) * (HH * WW)]);
      *reinterpret_cast<bf16x8*>(dst + c0) = v;
    }
  } else {
    // wb[s][co][kk], s = tap*4+cb, ci = (s&3)*32 + kk ; 4 elems/thread
    const int g = ((blk - NB * HH) * 256 + tid) * 4;
    const int s = g >> 13, rem = g & 8191;
    const int co = rem >> 5, kk0 = rem & 31;
    const int tap = s >> 2;
    bf16x4 o;
    #pragma unroll
    for (int i = 0; i < 4; ++i) {
      const int ci = ((s & 3) << 5) | (kk0 + i);
      o[i] = (short)f2bf(w[(co * CIN + ci) * NTAP + tap]);
    }
    *reinterpret_cast<bf16x4*>(wb + g) = o;
  }
}

// ---- main: K-split (2 blocks per (b,ho)), line-coop gather, atomic epilogue ----
__global__ __launch_bounds__(256, 4)
void dcn4(const ushort* __restrict__ xt, const float* __restrict__ off,
          const ushort* __restrict__ wb, float* __restrict__ out)
{
  __shared__ TapEntry taps[NTAP * WO];                    // 18432 B
  __shared__ __align__(16) ushort cols[2][4 * 64 * 8];    // 2 x 4096 B B-frag store

  const int tid  = threadIdx.x;
  // b in low 3 bits: all blocks of one image (both K-halves) land on one XCD
  const int b    = blockIdx.x & 7;
  const int ho   = (blockIdx.x >> 3) & 63;
  const int half = blockIdx.x >> 9;         // K-half: steps [half*18, half*18+18)
  const int S0   = half * HSTEP;

  for (int e = tid; e < NTAP * WO; e += 256) {
    const int k  = e >> 6;
    const int wo = e & 63;
    const float* op = off + (((size_t)(b * 18 + 2 * k) * HO + ho) * WO + wo);
    const float dy = op[0];
    const float dx = op[HO * WO];
    const float py  = (float)(ho - 1 + (k / 3)) + dy;
    const float pxf = (float)(wo - 1 + (k % 3)) + dx;
    const float y0f = floorf(py), x0f = floorf(pxf);
    const float fy = py - y0f, fx = pxf - x0f;
    const int y0 = (int)y0f, x0 = (int)x0f;
    const int y1 = y0 + 1,  x1 = x0 + 1;
    const bool vy0 = (unsigned)y0 < HH, vy1 = (unsigned)y1 < HH;
    const bool vx0 = (unsigned)x0 < WW, vx1 = (unsigned)x1 < WW;
    const int cy0 = min(max(y0, 0), HH - 1), cy1 = min(max(y1, 0), HH - 1);
    const int cx0 = min(max(x0, 0), WW - 1), cx1 = min(max(x1, 0), WW - 1);
    TapEntry t;
    t.i00 = (cy0 * WW + cx0) << 8;  t.i01 = (cy0 * WW + cx1) << 8;  // *CIN*2B
    t.i10 = (cy1 * WW + cx0) << 8;  t.i11 = (cy1 * WW + cx1) << 8;
    const float gy = 1.f - fy, gx = 1.f - fx;
    t.w00 = (vy0 && vx0) ? gy * gx : 0.f;
    t.w01 = (vy0 && vx1) ? gy * fx : 0.f;
    t.w10 = (vy1 && vx0) ? fy * gx : 0.f;
    t.w11 = (vy1 && vx1) ? fy * fx : 0.f;
    taps[e] = t;
  }

  const int lane = tid & 63;
  const int grp  = tid >> 6;   // wave id: px-group (producer) AND co-group (consumer)
  const int l15  = lane & 15;
  const int q    = lane >> 4;
  const int mypx = grp * 16 + l15;

  f32x4 acc[4][4];
  #pragma unroll
  for (int m = 0; m < 4; ++m)
    #pragma unroll
    for (int n = 0; n < 4; ++n)
      acc[m][n] = 0.f;

  const char* xb = reinterpret_cast<const char*>(xt) + (size_t)b * (HH * WW * CIN * 2);
  const ushort* wbg = wb + (grp * 64 + l15) * BK + q * 8;
  const int qb = q * 16;   // byte offset of my chunk within a 64B cb-block

  __syncthreads();   // taps ready

  bf16x8 aC[4], aN[4];
  // ---- prologue: A-frags for S0 + gather step S0 -> cols[0] ----
  {
    #pragma unroll
    for (int m = 0; m < 4; ++m)
      aC[m] = *reinterpret_cast<const bf16x8*>(
                  wbg + (size_t)S0 * (COUT * BK) + m * 16 * BK);
    const TapEntry te = taps[(S0 >> 2) * WO + mypx];
    const int cboff = (S0 & 3) * 64 + qb;
    const bf16x8 c00 = *reinterpret_cast<const bf16x8*>(xb + te.i00 + cboff);
    const bf16x8 c01 = *reinterpret_cast<const bf16x8*>(xb + te.i01 + cboff);
    const bf16x8 c10 = *reinterpret_cast<const bf16x8*>(xb + te.i10 + cboff);
    const bf16x8 c11 = *reinterpret_cast<const bf16x8*>(xb + te.i11 + cboff);
    bf16x8 hv;
    #pragma unroll
    for (int j = 0; j < 8; ++j) {
      const float v = te.w00 * bf2f(c00[j]) + te.w01 * bf2f(c01[j])
                    + te.w10 * bf2f(c10[j]) + te.w11 * bf2f(c11[j]);
      hv[j] = (short)f2bf(v);
    }
    *reinterpret_cast<bf16x8*>(
        reinterpret_cast<char*>(cols[0]) + (grp * 64 + lane) * 16) = hv;
  }
  __syncthreads();   // cols[0] ready

  #pragma unroll 2
  for (int t = 0; t < HSTEP; ++t) {
    const int cur = t & 1;
    const int sn  = S0 + t + 1;
    const bool live = (t + 1) < HSTEP;

    // next step's corner loads + A-frags: issue first (full-step latency cover)
    bf16x8 c00, c01, c10, c11;
    float w00, w01, w10, w11;
    if (live) {
      const TapEntry te = taps[(sn >> 2) * WO + mypx];
      const int cboff = (sn & 3) * 64 + qb;
      c00 = *reinterpret_cast<const bf16x8*>(xb + te.i00 + cboff);
      c01 = *reinterpret_cast<const bf16x8*>(xb + te.i01 + cboff);
      c10 = *reinterpret_cast<const bf16x8*>(xb + te.i10 + cboff);
      c11 = *reinterpret_cast<const bf16x8*>(xb + te.i11 + cboff);
      w00 = te.w00; w01 = te.w01; w10 = te.w10; w11 = te.w11;
      #pragma unroll
      for (int m = 0; m < 4; ++m)
        aN[m] = *reinterpret_cast<const bf16x8*>(
                    wbg + (size_t)sn * (COUT * BK) + m * 16 * BK);
    }

    // B-fragments for step t from LDS
    bf16x8 bb[4];
    #pragma unroll
    for (int n = 0; n < 4; ++n)
      bb[n] = *reinterpret_cast<const bf16x8*>(
          reinterpret_cast<const char*>(cols[cur]) + (n * 64 + lane) * 16);

    #pragma unroll
    for (int m = 0; m < 4; ++m)
      #pragma unroll
      for (int n = 0; n < 4; ++n)
        acc[m][n] = __builtin_amdgcn_mfma_f32_16x16x32_bf16(
            aC[m], bb[n], acc[m][n], 0, 0, 0);

    if (live) {
      bf16x8 hv;
      #pragma unroll
      for (int j = 0; j < 8; ++j) {
        const float v = w00 * bf2f(c00[j]) + w01 * bf2f(c01[j])
                      + w10 * bf2f(c10[j]) + w11 * bf2f(c11[j]);
        hv[j] = (short)f2bf(v);
      }
      *reinterpret_cast<bf16x8*>(
          reinterpret_cast<char*>(cols[cur ^ 1]) + (grp * 64 + lane) * 16) = hv;
      #pragma unroll
      for (int m = 0; m < 4; ++m)
        aC[m] = aN[m];
    }
    __syncthreads();
  }

  // ---- epilogue: atomic accumulate (exactly 2 contributions per address) ----
  #pragma unroll
  for (int m = 0; m < 4; ++m)
    #pragma unroll
    for (int n = 0; n < 4; ++n)
      #pragma unroll
      for (int r = 0; r < 4; ++r) {
        const int co = grp * 64 + m * 16 + q * 4 + r;
        const int wo = n * 16 + l15;
        unsafeAtomicAdd(&out[(((size_t)b * COUT + co) * HO + ho) * WO + wo],
                        acc[m][n][r]);
      }
}

// ---- fallback (ws too small): round-1 f32-gather path ----
__global__ __launch_bounds__(256, 2)
void dcn_f32(const float* __restrict__ x, const float* __restrict__ off,
             const float* __restrict__ wgt, float* __restrict__ out)
{
  __shared__ TapEntry taps[NTAP * WO];
  __shared__ __align__(16) ushort colsf[WO * 40];
  const int tid = threadIdx.x;
  const int b  = blockIdx.x & 7;
  const int ho = blockIdx.x >> 3;
  for (int e = tid; e < NTAP * WO; e += 256) {
    const int k  = e >> 6;
    const int wo = e & 63;
    const float* op = off + (((size_t)(b * 18 + 2 * k) * HO + ho) * WO + wo);
    const float dy = op[0];
    const float dx = op[HO * WO];
    const float py  = (float)(ho - 1 + (k / 3)) + dy;
    const float pxf = (float)(wo - 1 + (k % 3)) + dx;
    const float y0f = floorf(py), x0f = floorf(pxf);
    const float fy = py - y0f, fx = pxf - x0f;
    const int y0 = (int)y0f, x0 = (int)x0f;
    const int y1 = y0 + 1,  x1 = x0 + 1;
    const bool vy0 = (unsigned)y0 < HH, vy1 = (unsigned)y1 < HH;
    const bool vx0 = (unsigned)x0 < WW, vx1 = (unsigned)x1 < WW;
    const int cy0 = min(max(y0, 0), HH - 1), cy1 = min(max(y1, 0), HH - 1);
    const int cx0 = min(max(x0, 0), WW - 1), cx1 = min(max(x1, 0), WW - 1);
    TapEntry t;
    t.i00 = cy0 * WW + cx0; t.i01 = cy0 * WW + cx1;
    t.i10 = cy1 * WW + cx0; t.i11 = cy1 * WW + cx1;
    const float gy = 1.f - fy, gx = 1.f - fx;
    t.w00 = (vy0 && vx0) ? gy * gx : 0.f;
    t.w01 = (vy0 && vx1) ? gy * fx : 0.f;
    t.w10 = (vy1 && vx0) ? fy * gx : 0.f;
    t.w11 = (vy1 && vx1) ? fy * fx : 0.f;
    taps[e] = t;
  }
  const int px = tid & 63, grp = tid >> 6, lane = tid & 63;
  const int l15 = lane & 15, q = lane >> 4;
  f32x4 acc[4][4];
  #pragma unroll
  for (int m = 0; m < 4; ++m)
    #pragma unroll
    for (int n = 0; n < 4; ++n) acc[m][n] = 0.f;
  const float* xb = x + (size_t)b * CIN * HH * WW;
  __syncthreads();
  for (int tap = 0; tap < NTAP; ++tap) {
    const TapEntry e = taps[tap * WO + px];
    for (int cb = 0; cb < 4; ++cb) {
      __syncthreads();
      {
        const float* xp = xb + (size_t)(cb * 32 + grp * 8) * (HH * WW);
        bf16x8 hv;
        #pragma unroll
        for (int j = 0; j < 8; ++j) {
          const float* p = xp + j * (HH * WW);
          const float v = e.w00 * p[e.i00] + e.w01 * p[e.i01]
                        + e.w10 * p[e.i10] + e.w11 * p[e.i11];
          hv[j] = (short)f2bf(v);
        }
        *reinterpret_cast<bf16x8*>(
            reinterpret_cast<char*>(colsf) + px * 80 + grp * 16) = hv;
      }
      __syncthreads();
      bf16x8 a[4], bbf[4];
      #pragma unroll
      for (int m = 0; m < 4; ++m) {
        const int co = grp * 64 + m * 16 + l15;
        bf16x8 t;
        #pragma unroll
        for (int j = 0; j < 8; ++j)
          t[j] = (short)f2bf(wgt[(size_t)(co * CIN + cb * 32 + q * 8 + j) * NTAP + tap]);
        a[m] = t;
      }
      #pragma unroll
      for (int n = 0; n < 4; ++n)
        bbf[n] = *reinterpret_cast<const bf16x8*>(
            reinterpret_cast<const char*>(colsf) + (n * 16 + l15) * 80 + q * 16);
      #pragma unroll
      for (int m = 0; m < 4; ++m)
        #pragma unroll
        for (int n = 0; n < 4; ++n)
          acc[m][n] = __builtin_amdgcn_mfma_f32_16x16x32_bf16(
              a[m], bbf[n], acc[m][n], 0, 0, 0);
    }
  }
  const int wco = grp * 64;
  #pragma unroll
  for (int m = 0; m < 4; ++m)
    #pragma unroll
    for (int n = 0; n < 4; ++n)
      #pragma unroll
      for (int r = 0; r < 4; ++r) {
        const int co = wco + m * 16 + q * 4 + r;
        const int wo = n * 16 + l15;
        out[(((size_t)b * COUT + co) * HO + ho) * WO + wo] = acc[m][n][r];
      }
}

extern "C" void kernel_launch(void* const* d_in, const int* in_sizes, int n_in,
                              void* d_out, int out_size, void* d_ws, size_t ws_size,
                              hipStream_t stream) {
  const float* x   = (const float*)d_in[0];   // [8,128,64,64]
  const float* off = (const float*)d_in[1];   // [8,18,64,64]
  const float* wgt = (const float*)d_in[2];   // [256,128,3,3]
  float* out = (float*)d_out;                 // [8,256,64,64]

  const size_t xt_bytes = (size_t)NB * HH * WW * CIN * sizeof(ushort);   // 8 MiB
  const size_t wb_bytes = (size_t)NSTEP * COUT * BK * sizeof(ushort);    // 576 KiB
  if (ws_size >= xt_bytes + wb_bytes) {
    ushort* xtp = (ushort*)d_ws;
    ushort* wbp = (ushort*)((char*)d_ws + xt_bytes);
    const int wblocks = (NSTEP * COUT * BK) / 1024;   // 288
    prep<<<NB * HH + wblocks, 256, 0, stream>>>(x, wgt, xtp, wbp);
    hipMemsetAsync(out, 0, (size_t)out_size * sizeof(float), stream);
    dcn4<<<NB * HO * 2, 256, 0, stream>>>(xtp, off, wbp, out);
  } else {
    dcn_f32<<<NB * HO, 256, 0, stream>>>(x, off, wgt, out);
  }
}

// Round 6
// 49.712 us; speedup vs baseline: 2.6328x; 2.6328x over previous
//
#include <hip/hip_runtime.h>
#include <hip/hip_bf16.h>

#define CIN   128
#define HH    64
#define WW    64
#define COUT  256
#define HO    64
#define WO    64
#define NTAP  9
#define KTOT  (CIN*NTAP)   /* 1152 */
#define BK    32
#define NSTEP (KTOT/BK)    /* 36 */
#define NB    8
#define CROW  272          /* cols row stride in bytes (256 data + 16 pad) */

typedef __attribute__((ext_vector_type(8))) short bf16x8;
typedef __attribute__((ext_vector_type(4))) short bf16x4;
typedef __attribute__((ext_vector_type(4))) float f32x4;

struct __align__(16) TapEntry {
  int   i00, i01, i10, i11;    // BYTE offsets into xt's per-image slice (256B units)
  float w00, w01, w10, w11;
};

static __device__ __forceinline__ ushort f2bf(float v) {
  unsigned u = __float_as_uint(v);
  unsigned rnd = 0x7fffu + ((u >> 16) & 1u);
  return (ushort)((u + rnd) >> 16);
}
static __device__ __forceinline__ float bf2f(short s) {
  return __uint_as_float(((unsigned)(unsigned short)s) << 16);
}

// ---- prep: x NCHW f32 -> xt NHWC bf16  +  weight repack to wbt ----
// wbt element (s, c16, lane=q*16+r, j) = w[co=c16*16+r][ci=(s&3)*32+q*8+j][tap=s>>2]
// so a wave's A-frag load for (s, c16) is lane*16B contiguous (1KB).
__global__ __launch_bounds__(256) void prep(const float* __restrict__ x,
                                            const float* __restrict__ w,
                                            ushort* __restrict__ xt,
                                            ushort* __restrict__ wbt) {
  const int blk = blockIdx.x;
  const int tid = threadIdx.x;
  if (blk < NB * HH) {
    const int b = blk >> 6, y = blk & 63;
    const int px = tid & 63, c8 = tid >> 6;
    const float* src = x + (size_t)b * CIN * HH * WW + y * WW + px;
    ushort* dst = xt + (((size_t)(b * HH + y) * WW) + px) * CIN;
    #pragma unroll
    for (int cc = 0; cc < 4; ++cc) {
      const int c0 = cc * 32 + c8 * 8;
      bf16x8 v;
      #pragma unroll
      for (int j = 0; j < 8; ++j)
        v[j] = (short)f2bf(src[(size_t)(c0 + j) * (HH * WW)]);
      *reinterpret_cast<bf16x8*>(dst + c0) = v;
    }
  } else {
    // one 16B chunk (8 elements) per thread; 36864 chunks total
    const int h = (blk - NB * HH) * 256 + tid;
    const int s   = h >> 10;
    const int c16 = (h >> 6) & 15;
    const int l   = h & 63;
    const int q   = l >> 4;
    const int r   = l & 15;
    const int co  = c16 * 16 + r;
    const int tap = s >> 2;
    const int ci0 = (s & 3) * 32 + q * 8;
    bf16x8 o;
    #pragma unroll
    for (int j = 0; j < 8; ++j)
      o[j] = (short)f2bf(w[(size_t)(co * CIN + ci0 + j) * NTAP + tap]);
    *reinterpret_cast<bf16x8*>(wbt + (size_t)h * 8) = o;
  }
}

// ---- main: tap-granular coalesced gather + implicit GEMM ----
__global__ __launch_bounds__(256, 2)
void dcn5(const ushort* __restrict__ xt, const float* __restrict__ off,
          const ushort* __restrict__ wbt, float* __restrict__ out)
{
  __shared__ TapEntry taps[NTAP * WO];                 // 18432 B
  __shared__ __align__(16) char colsB[WO * CROW];      // 64 rows x 272B = 17408 B

  const int tid = threadIdx.x;
  // b in low 3 bits: all 64 blocks of one image land on one XCD (L2 locality)
  const int b  = blockIdx.x & 7;
  const int ho = blockIdx.x >> 3;

  for (int e = tid; e < NTAP * WO; e += 256) {
    const int k  = e >> 6;
    const int wo = e & 63;
    const float* op = off + (((size_t)(b * 18 + 2 * k) * HO + ho) * WO + wo);
    const float dy = op[0];
    const float dx = op[HO * WO];
    const float py  = (float)(ho - 1 + (k / 3)) + dy;
    const float pxf = (float)(wo - 1 + (k % 3)) + dx;
    const float y0f = floorf(py), x0f = floorf(pxf);
    const float fy = py - y0f, fx = pxf - x0f;
    const int y0 = (int)y0f, x0 = (int)x0f;
    const int y1 = y0 + 1,  x1 = x0 + 1;
    const bool vy0 = (unsigned)y0 < HH, vy1 = (unsigned)y1 < HH;
    const bool vx0 = (unsigned)x0 < WW, vx1 = (unsigned)x1 < WW;
    const int cy0 = min(max(y0, 0), HH - 1), cy1 = min(max(y1, 0), HH - 1);
    const int cx0 = min(max(x0, 0), WW - 1), cx1 = min(max(x1, 0), WW - 1);
    TapEntry t;
    t.i00 = (cy0 * WW + cx0) << 8;  t.i01 = (cy0 * WW + cx1) << 8;  // *CIN*2B
    t.i10 = (cy1 * WW + cx0) << 8;  t.i11 = (cy1 * WW + cx1) << 8;
    const float gy = 1.f - fy, gx = 1.f - fx;
    t.w00 = (vy0 && vx0) ? gy * gx : 0.f;
    t.w01 = (vy0 && vx1) ? gy * fx : 0.f;
    t.w10 = (vy1 && vx0) ? fy * gx : 0.f;
    t.w11 = (vy1 && vx1) ? fy * fx : 0.f;
    taps[e] = t;
  }

  const int lane = tid & 63;
  const int grp  = tid >> 6;   // wave id: px-group (producer) AND co-group (consumer)
  const int l15  = lane & 15;
  const int q    = lane >> 4;
  const int g    = q;          // gather: pixel-subindex within quad
  const int s16  = l15;        // gather: 16B chunk within 256B channel row

  f32x4 acc[4][4];
  #pragma unroll
  for (int m = 0; m < 4; ++m)
    #pragma unroll
    for (int n = 0; n < 4; ++n)
      acc[m][n] = 0.f;

  const char* xb = reinterpret_cast<const char*>(xt)
                 + (size_t)b * (HH * WW * CIN * 2) + s16 * 16;

  __syncthreads();   // taps ready

  #pragma unroll 1
  for (int tap = 0; tap < NTAP; ++tap) {
    // ---- gather to registers: 4 pixels x 4 corners, 16B/lane, all 128 ch ----
    // lanes 0-15 of each 16-lane group read one pixel-corner's contiguous 256B
    bf16x8 hv[4];
    #pragma unroll
    for (int pq = 0; pq < 4; ++pq) {
      const int px = (grp << 4) + (pq << 2) + g;
      const TapEntry te = taps[tap * WO + px];
      const bf16x8 c00 = *reinterpret_cast<const bf16x8*>(xb + te.i00);
      const bf16x8 c01 = *reinterpret_cast<const bf16x8*>(xb + te.i01);
      const bf16x8 c10 = *reinterpret_cast<const bf16x8*>(xb + te.i10);
      const bf16x8 c11 = *reinterpret_cast<const bf16x8*>(xb + te.i11);
      bf16x8 h;
      #pragma unroll
      for (int j = 0; j < 8; ++j) {
        const float v = te.w00 * bf2f(c00[j]) + te.w01 * bf2f(c01[j])
                      + te.w10 * bf2f(c10[j]) + te.w11 * bf2f(c11[j]);
        h[j] = (short)f2bf(v);
      }
      hv[pq] = h;
    }

    __syncthreads();   // previous tap's consumers done with colsB

    #pragma unroll
    for (int pq = 0; pq < 4; ++pq) {
      const int px = (grp << 4) + (pq << 2) + g;
      *reinterpret_cast<bf16x8*>(colsB + px * CROW + s16 * 16) = hv[pq];
    }

    __syncthreads();   // colsB ready

    // ---- 4 barrier-free K-steps: A direct from wbt (1KB/wave contiguous) ----
    #pragma unroll
    for (int kk = 0; kk < 4; ++kk) {
      const int s = tap * 4 + kk;
      bf16x8 a[4], bb[4];
      #pragma unroll
      for (int m = 0; m < 4; ++m)
        a[m] = *reinterpret_cast<const bf16x8*>(
            wbt + ((size_t)((s * 16 + grp * 4 + m) * 64 + lane)) * 8);
      #pragma unroll
      for (int n = 0; n < 4; ++n)
        bb[n] = *reinterpret_cast<const bf16x8*>(
            colsB + (n * 16 + l15) * CROW + kk * 64 + q * 16);
      #pragma unroll
      for (int m = 0; m < 4; ++m)
        #pragma unroll
        for (int n = 0; n < 4; ++n)
          acc[m][n] = __builtin_amdgcn_mfma_f32_16x16x32_bf16(
              a[m], bb[n], acc[m][n], 0, 0, 0);
    }
  }

  // ---- epilogue: D row(co) = q*4+r (+m*16), col(wo) = l15 (+n*16) ----
  #pragma unroll
  for (int m = 0; m < 4; ++m)
    #pragma unroll
    for (int n = 0; n < 4; ++n)
      #pragma unroll
      for (int r = 0; r < 4; ++r) {
        const int co = grp * 64 + m * 16 + q * 4 + r;
        const int wo = n * 16 + l15;
        out[(((size_t)b * COUT + co) * HO + ho) * WO + wo] = acc[m][n][r];
      }
}

// ---- fallback (ws too small): round-1 f32-gather path ----
__global__ __launch_bounds__(256, 2)
void dcn_f32(const float* __restrict__ x, const float* __restrict__ off,
             const float* __restrict__ wgt, float* __restrict__ out)
{
  __shared__ TapEntry taps[NTAP * WO];
  __shared__ __align__(16) ushort colsf[WO * 40];
  const int tid = threadIdx.x;
  const int b  = blockIdx.x & 7;
  const int ho = blockIdx.x >> 3;
  for (int e = tid; e < NTAP * WO; e += 256) {
    const int k  = e >> 6;
    const int wo = e & 63;
    const float* op = off + (((size_t)(b * 18 + 2 * k) * HO + ho) * WO + wo);
    const float dy = op[0];
    const float dx = op[HO * WO];
    const float py  = (float)(ho - 1 + (k / 3)) + dy;
    const float pxf = (float)(wo - 1 + (k % 3)) + dx;
    const float y0f = floorf(py), x0f = floorf(pxf);
    const float fy = py - y0f, fx = pxf - x0f;
    const int y0 = (int)y0f, x0 = (int)x0f;
    const int y1 = y0 + 1,  x1 = x0 + 1;
    const bool vy0 = (unsigned)y0 < HH, vy1 = (unsigned)y1 < HH;
    const bool vx0 = (unsigned)x0 < WW, vx1 = (unsigned)x1 < WW;
    const int cy0 = min(max(y0, 0), HH - 1), cy1 = min(max(y1, 0), HH - 1);
    const int cx0 = min(max(x0, 0), WW - 1), cx1 = min(max(x1, 0), WW - 1);
    TapEntry t;
    t.i00 = cy0 * WW + cx0; t.i01 = cy0 * WW + cx1;
    t.i10 = cy1 * WW + cx0; t.i11 = cy1 * WW + cx1;
    const float gy = 1.f - fy, gx = 1.f - fx;
    t.w00 = (vy0 && vx0) ? gy * gx : 0.f;
    t.w01 = (vy0 && vx1) ? gy * fx : 0.f;
    t.w10 = (vy1 && vx0) ? fy * gx : 0.f;
    t.w11 = (vy1 && vx1) ? fy * fx : 0.f;
    taps[e] = t;
  }
  const int px = tid & 63, grp = tid >> 6, lane = tid & 63;
  const int l15 = lane & 15, q = lane >> 4;
  f32x4 acc[4][4];
  #pragma unroll
  for (int m = 0; m < 4; ++m)
    #pragma unroll
    for (int n = 0; n < 4; ++n) acc[m][n] = 0.f;
  const float* xb = x + (size_t)b * CIN * HH * WW;
  __syncthreads();
  for (int tap = 0; tap < NTAP; ++tap) {
    const TapEntry e = taps[tap * WO + px];
    for (int cb = 0; cb < 4; ++cb) {
      __syncthreads();
      {
        const float* xp = xb + (size_t)(cb * 32 + grp * 8) * (HH * WW);
        bf16x8 hv;
        #pragma unroll
        for (int j = 0; j < 8; ++j) {
          const float* p = xp + j * (HH * WW);
          const float v = e.w00 * p[e.i00] + e.w01 * p[e.i01]
                        + e.w10 * p[e.i10] + e.w11 * p[e.i11];
          hv[j] = (short)f2bf(v);
        }
        *reinterpret_cast<bf16x8*>(
            reinterpret_cast<char*>(colsf) + px * 80 + grp * 16) = hv;
      }
      __syncthreads();
      bf16x8 a[4], bbf[4];
      #pragma unroll
      for (int m = 0; m < 4; ++m) {
        const int co = grp * 64 + m * 16 + l15;
        bf16x8 t;
        #pragma unroll
        for (int j = 0; j < 8; ++j)
          t[j] = (short)f2bf(wgt[(size_t)(co * CIN + cb * 32 + q * 8 + j) * NTAP + tap]);
        a[m] = t;
      }
      #pragma unroll
      for (int n = 0; n < 4; ++n)
        bbf[n] = *reinterpret_cast<const bf16x8*>(
            reinterpret_cast<const char*>(colsf) + (n * 16 + l15) * 80 + q * 16);
      #pragma unroll
      for (int m = 0; m < 4; ++m)
        #pragma unroll
        for (int n = 0; n < 4; ++n)
          acc[m][n] = __builtin_amdgcn_mfma_f32_16x16x32_bf16(
              a[m], bbf[n], acc[m][n], 0, 0, 0);
    }
  }
  const int wco = grp * 64;
  #pragma unroll
  for (int m = 0; m < 4; ++m)
    #pragma unroll
    for (int n = 0; n < 4; ++n)
      #pragma unroll
      for (int r = 0; r < 4; ++r) {
        const int co = wco + m * 16 + q * 4 + r;
        const int wo = n * 16 + l15;
        out[(((size_t)b * COUT + co) * HO + ho) * WO + wo] = acc[m][n][r];
      }
}

extern "C" void kernel_launch(void* const* d_in, const int* in_sizes, int n_in,
                              void* d_out, int out_size, void* d_ws, size_t ws_size,
                              hipStream_t stream) {
  const float* x   = (const float*)d_in[0];   // [8,128,64,64]
  const float* off = (const float*)d_in[1];   // [8,18,64,64]
  const float* wgt = (const float*)d_in[2];   // [256,128,3,3]
  float* out = (float*)d_out;                 // [8,256,64,64]

  const size_t xt_bytes = (size_t)NB * HH * WW * CIN * sizeof(ushort);   // 8 MiB
  const size_t wb_bytes = (size_t)NSTEP * COUT * BK * sizeof(ushort);    // 576 KiB
  if (ws_size >= xt_bytes + wb_bytes) {
    ushort* xtp  = (ushort*)d_ws;
    ushort* wbtp = (ushort*)((char*)d_ws + xt_bytes);
    const int wchunks = NSTEP * COUT * BK / 8;        // 36864 16B chunks
    const int wblocks = wchunks / 256;                // 144
    prep<<<NB * HH + wblocks, 256, 0, stream>>>(x, wgt, xtp, wbtp);
    dcn5<<<NB * HO, 256, 0, stream>>>(xtp, off, wbtp, out);
  } else {
    dcn_f32<<<NB * HO, 256, 0, stream>>>(x, off, wgt, out);
  }
}